// Round 1
// baseline (727.243 us; speedup 1.0000x reference)
//
#include <hip/hip_runtime.h>
#include <math.h>

#define DEV static __device__ __forceinline__

// ---------------- 4-qubit real-amplitude circuit helpers ----------------
// state index: idx = q0*8 + q1*4 + q2*2 + q3  (wire w <-> bit (8>>w))
// Wire indices are TEMPLATE params so all register-array indices are
// compile-time (runtime-indexed ext arrays spill to scratch).
template <int W>
DEV void q_ry(float s[16], float th) {
  float c = cosf(th * 0.5f), sn = sinf(th * 0.5f);
  constexpr int m = 8 >> W;
#pragma unroll
  for (int i = 0; i < 16; ++i) {
    if (!(i & m)) {
      float a = s[i], b = s[i | m];
      s[i] = c * a - sn * b;
      s[i | m] = sn * a + c * b;
    }
  }
}
template <int C, int T>
DEV void q_cnot(float s[16]) {
  constexpr int mc = 8 >> C, mt = 8 >> T;
#pragma unroll
  for (int i = 0; i < 16; ++i) {
    if ((i & mc) && !(i & mt)) {
      float t = s[i]; s[i] = s[i | mt]; s[i | mt] = t;
    }
  }
}
template <int W>
DEV float q_mz(const float s[16]) {
  constexpr int m = 8 >> W;
  float p = 0.f;
#pragma unroll
  for (int i = 0; i < 16; ++i) p += (i & m) ? -s[i] * s[i] : s[i] * s[i];
  return p;
}
DEV void q_layer(float s[16], const float* __restrict__ th) {
  q_ry<0>(s, th[0]); q_cnot<0, 1>(s);
  q_ry<1>(s, th[1]); q_cnot<1, 2>(s);
  q_ry<2>(s, th[2]); q_cnot<2, 3>(s);
  q_ry<3>(s, th[3]); q_cnot<3, 0>(s);
}

// ---------------- conv1 (5x5 s2 p1, 3->6) + relu + pool(2x2 s1) ----------------
// x: (128,3,249,249) -> pooled out: (128,6,123,123)
__global__ __launch_bounds__(256) void k_conv1(const float* __restrict__ x,
                                               const float* __restrict__ w,
                                               const float* __restrict__ bia,
                                               float* __restrict__ out) {
  __shared__ float xs[3][37][37];   // input tile (span = 16*2+5)
  __shared__ float wsm[75];         // w[co] slice (3*5*5)
  __shared__ float ct[17][17];      // conv subtile
  int bz = blockIdx.z;
  int b = bz / 6, co = bz % 6;
  int py0 = blockIdx.y * 16, px0 = blockIdx.x * 16;
  int iy0 = py0 * 2 - 1, ix0 = px0 * 2 - 1;
  int tid = threadIdx.x;
  if (tid < 75) wsm[tid] = w[co * 75 + tid];
  const float* xb = x + (size_t)b * 186003;  // 3*249*249
  for (int idx = tid; idx < 3 * 37 * 37; idx += 256) {
    int ci = idx / 1369, r = (idx % 1369) / 37, cc = idx % 37;
    int iy = iy0 + r, ix = ix0 + cc;
    float v = 0.f;
    if (iy >= 0 && iy < 249 && ix >= 0 && ix < 249)
      v = xb[ci * 62001 + iy * 249 + ix];
    xs[ci][r][cc] = v;
  }
  __syncthreads();
  float bv = bia[co];
  for (int idx = tid; idx < 17 * 17; idx += 256) {
    int ty = idx / 17, tx = idx % 17;
    float acc = bv;
#pragma unroll
    for (int ci = 0; ci < 3; ++ci)
#pragma unroll
      for (int ky = 0; ky < 5; ++ky)
#pragma unroll
        for (int kx = 0; kx < 5; ++kx)
          acc += xs[ci][ty * 2 + ky][tx * 2 + kx] * wsm[ci * 25 + ky * 5 + kx];
    ct[ty][tx] = acc;
  }
  __syncthreads();
  int ty = tid / 16, tx = tid % 16;
  int py = py0 + ty, px = px0 + tx;
  if (py < 123 && px < 123) {
    float m = fmaxf(fmaxf(ct[ty][tx], ct[ty][tx + 1]),
                    fmaxf(ct[ty + 1][tx], ct[ty + 1][tx + 1]));
    out[((size_t)(b * 6 + co) * 123 + py) * 123 + px] = fmaxf(m, 0.f);
  }
}

// ---------------- conv2 (3x3 s2 p1, 6->15) + relu + pool ----------------
// in: (128,6,123,123) -> h: (128, 15*61*61=55815) flattened
__global__ __launch_bounds__(256) void k_conv2(const float* __restrict__ in,
                                               const float* __restrict__ w,
                                               const float* __restrict__ bia,
                                               float* __restrict__ out) {
  __shared__ float xs[6][35][35];   // span = 16*2+3
  __shared__ float wsm[54];
  __shared__ float ct[17][17];
  int bz = blockIdx.z;
  int b = bz / 15, co = bz % 15;
  int py0 = blockIdx.y * 16, px0 = blockIdx.x * 16;
  int iy0 = py0 * 2 - 1, ix0 = px0 * 2 - 1;
  int tid = threadIdx.x;
  if (tid < 54) wsm[tid] = w[co * 54 + tid];
  const float* ib = in + (size_t)b * 90774;  // 6*123*123
  for (int idx = tid; idx < 6 * 35 * 35; idx += 256) {
    int ci = idx / 1225, r = (idx % 1225) / 35, cc = idx % 35;
    int iy = iy0 + r, ix = ix0 + cc;
    float v = 0.f;
    if (iy >= 0 && iy < 123 && ix >= 0 && ix < 123)
      v = ib[ci * 15129 + iy * 123 + ix];
    xs[ci][r][cc] = v;
  }
  __syncthreads();
  float bv = bia[co];
  for (int idx = tid; idx < 17 * 17; idx += 256) {
    int ty = idx / 17, tx = idx % 17;
    float acc = bv;
#pragma unroll
    for (int ci = 0; ci < 6; ++ci)
#pragma unroll
      for (int ky = 0; ky < 3; ++ky)
#pragma unroll
        for (int kx = 0; kx < 3; ++kx)
          acc += xs[ci][ty * 2 + ky][tx * 2 + kx] * wsm[ci * 9 + ky * 3 + kx];
    ct[ty][tx] = acc;
  }
  __syncthreads();
  int ty = tid / 16, tx = tid % 16;
  int py = py0 + ty, px = px0 + tx;
  if (py < 61 && px < 61) {
    float m = fmaxf(fmaxf(ct[ty][tx], ct[ty][tx + 1]),
                    fmaxf(ct[ty + 1][tx], ct[ty + 1][tx + 1]));
    out[(size_t)b * 55815 + co * 3721 + py * 61 + px] = fmaxf(m, 0.f);
  }
}

// ---------------- fc1: (128,55815) x (120,55815)^T, split-K partials ----------------
#define KFC 55815
#define NCHUNK 1745  // ceil(55815/32)
__global__ __launch_bounds__(256) void k_fc1(const float* __restrict__ h,
                                             const float* __restrict__ w,
                                             float* __restrict__ partial) {
  __shared__ float hs[128][33];   // +1 pad: kills b*32+k bank collision
  __shared__ float wsd[120][33];
  int tid = threadIdx.x;
  int tb = tid & 31;   // batch lane: batches tb, tb+32, tb+64, tb+96
  int bo = tid >> 5;   // output group: outputs bo*15 .. bo*15+14
  float acc[4][15];
#pragma unroll
  for (int j = 0; j < 4; ++j)
#pragma unroll
    for (int oo = 0; oo < 15; ++oo) acc[j][oo] = 0.f;

  for (int ch = blockIdx.x; ch < NCHUNK; ch += gridDim.x) {
    int k0 = ch * 32;
    for (int idx = tid; idx < 128 * 32; idx += 256) {
      int bb = idx >> 5, kk = idx & 31;
      int k = k0 + kk;
      hs[bb][kk] = (k < KFC) ? h[(size_t)bb * KFC + k] : 0.f;
    }
    for (int idx = tid; idx < 120 * 32; idx += 256) {
      int oo = idx >> 5, kk = idx & 31;
      int k = k0 + kk;
      wsd[oo][kk] = (k < KFC) ? w[(size_t)oo * KFC + k] : 0.f;
    }
    __syncthreads();
#pragma unroll 4
    for (int kk = 0; kk < 32; ++kk) {
      float hv[4], wv[15];
#pragma unroll
      for (int j = 0; j < 4; ++j) hv[j] = hs[tb + 32 * j][kk];
#pragma unroll
      for (int oo = 0; oo < 15; ++oo) wv[oo] = wsd[bo * 15 + oo][kk];
#pragma unroll
      for (int j = 0; j < 4; ++j)
#pragma unroll
        for (int oo = 0; oo < 15; ++oo) acc[j][oo] += hv[j] * wv[oo];
    }
    __syncthreads();
  }
  float* pg = partial + (size_t)blockIdx.x * 15360;
#pragma unroll
  for (int j = 0; j < 4; ++j) {
    int b = tb + 32 * j;
#pragma unroll
    for (int oo = 0; oo < 15; ++oo) pg[b * 120 + bo * 15 + oo] = acc[j][oo];
  }
}

__global__ __launch_bounds__(256) void k_fc1_reduce(const float* __restrict__ partial,
                                                    const float* __restrict__ bias,
                                                    float* __restrict__ outv) {
  int i = blockIdx.x * 256 + threadIdx.x;
  if (i >= 15360) return;
  float a = bias[i % 120];
  for (int g = 0; g < 256; ++g) a += partial[(size_t)g * 15360 + i];
  outv[i] = fmaxf(a, 0.f);  // relu fused
}

// ---------------- fc2 + fc3 + quantum head -> probs_conv ----------------
__global__ __launch_bounds__(128) void k_head(const float* __restrict__ fc1o,
                                              const float* __restrict__ w2,
                                              const float* __restrict__ b2,
                                              const float* __restrict__ w3,
                                              const float* __restrict__ b3,
                                              const float* __restrict__ hth,
                                              float* __restrict__ probs_conv) {
  __shared__ float h1[120];
  __shared__ float h2[84];
  int b = blockIdx.x, tid = threadIdx.x;
  if (tid < 120) h1[tid] = fc1o[b * 120 + tid];  // already relu'd
  __syncthreads();
  if (tid < 84) {
    float a = b2[tid];
    for (int k = 0; k < 120; ++k) a += h1[k] * w2[tid * 120 + k];
    h2[tid] = fmaxf(a, 0.f);
  }
  __syncthreads();
  if (tid == 0) {
    float lg = b3[0];
    for (int j = 0; j < 84; ++j) lg += h2[j] * w3[j];
    float s[16];
#pragma unroll
    for (int i = 0; i < 16; ++i) s[i] = 0.f;
    s[0] = 1.f;
    q_ry<0>(s, lg);
    q_layer(s, hth);
    float z = q_mz<0>(s);
    probs_conv[b] = 1.f / (1.f + expf(-z));
  }
}

// ---------------- resize 249->28 (jax linear+antialias), row pass ----------------
DEV void resize_win(int o, int& i0, int& i1, float& sf, float& inorm) {
  const float invs = 249.0f / 28.0f;   // = kernel_scale (antialias, scale<1)
  sf = ((float)o + 0.5f) * invs - 0.5f;
  i0 = (int)ceilf(sf - invs); if (i0 < 0) i0 = 0;
  i1 = (int)floorf(sf + invs); if (i1 > 248) i1 = 248;
  float nrm = 0.f;
  for (int i = i0; i <= i1; ++i)
    nrm += fmaxf(0.f, 1.f - fabsf(sf - (float)i) * (28.0f / 249.0f));
  inorm = 1.f / nrm;
}

// tmp[b][oy][ix] = sum_iy W[oy][iy] * gray[b][iy][ix]
__global__ __launch_bounds__(256) void k_resize_rows(const float* __restrict__ x,
                                                     float* __restrict__ tmp) {
  int b = blockIdx.x / 28, oy = blockIdx.x % 28;
  int ix = threadIdx.x;
  if (ix >= 249) return;
  int i0, i1; float sf, inorm;
  resize_win(oy, i0, i1, sf, inorm);
  const float* xb = x + (size_t)b * 186003;
  float acc = 0.f;
  for (int iy = i0; iy <= i1; ++iy) {
    float wv = fmaxf(0.f, 1.f - fabsf(sf - (float)iy) * (28.0f / 249.0f)) * inorm;
    float gr = (xb[iy * 249 + ix] + xb[62001 + iy * 249 + ix] +
                xb[124002 + iy * 249 + ix]) * (1.0f / 3.0f);
    acc += wv * gr;
  }
  tmp[((size_t)b * 28 + oy) * 249 + ix] = acc;
}

// ---------------- col pass + patches + per-patch circuits + lin + combine ----------------
__global__ __launch_bounds__(256) void k_quanv(const float* __restrict__ tmp,
                                               const float* __restrict__ qth,
                                               const float* __restrict__ lw,
                                               const float* __restrict__ lb,
                                               const float* __restrict__ probs_conv,
                                               float* __restrict__ out) {
  __shared__ float g[784];
  __shared__ float red[4];
  int b = blockIdx.x, tid = threadIdx.x;
  for (int idx = tid; idx < 784; idx += 256) {
    int oy = idx / 28, ox = idx % 28;
    int i0, i1; float sf, inorm;
    resize_win(ox, i0, i1, sf, inorm);
    const float* tr = tmp + ((size_t)b * 28 + oy) * 249;
    float acc = 0.f;
    for (int i = i0; i <= i1; ++i)
      acc += fmaxf(0.f, 1.f - fabsf(sf - (float)i) * (28.0f / 249.0f)) * inorm * tr[i];
    g[idx] = acc;
  }
  __syncthreads();
  float part = 0.f;
  if (tid < 196) {
    int pi = tid / 14, pj = tid % 14;
    float v0 = g[(2 * pi) * 28 + 2 * pj];
    float v1 = g[(2 * pi) * 28 + 2 * pj + 1];
    float v2 = g[(2 * pi + 1) * 28 + 2 * pj];
    float v3 = g[(2 * pi + 1) * 28 + 2 * pj + 1];
    float s[16];
#pragma unroll
    for (int i = 0; i < 16; ++i) s[i] = 0.f;
    s[0] = 1.f;
    q_ry<0>(s, v0); q_ry<1>(s, v1); q_ry<2>(s, v2); q_ry<3>(s, v3);
    q_layer(s, qth);
    float z0 = q_mz<0>(s), z1 = q_mz<1>(s), z2 = q_mz<2>(s), z3 = q_mz<3>(s);
    const float* lwp = lw + tid * 4;
    part = z0 * lwp[0] + z1 * lwp[1] + z2 * lwp[2] + z3 * lwp[3];
  }
#pragma unroll
  for (int off = 32; off > 0; off >>= 1) part += __shfl_down(part, off, 64);
  if ((tid & 63) == 0) red[tid >> 6] = part;
  __syncthreads();
  if (tid == 0) {
    float tot = red[0] + red[1] + red[2] + red[3] + lb[0];
    float pq = 1.f / (1.f + expf(-tot));
    float pr = 0.5f * (probs_conv[b] + pq);
    out[b * 2 + 0] = pr;
    out[b * 2 + 1] = 1.f - pr;
  }
}

// ---------------- launch ----------------
extern "C" void kernel_launch(void* const* d_in, const int* in_sizes, int n_in,
                              void* d_out, int out_size, void* d_ws, size_t ws_size,
                              hipStream_t stream) {
  const float* x   = (const float*)d_in[0];
  const float* c1w = (const float*)d_in[1];
  const float* c1b = (const float*)d_in[2];
  const float* c2w = (const float*)d_in[3];
  const float* c2b = (const float*)d_in[4];
  const float* f1w = (const float*)d_in[5];
  const float* f1b = (const float*)d_in[6];
  const float* f2w = (const float*)d_in[7];
  const float* f2b = (const float*)d_in[8];
  const float* f3w = (const float*)d_in[9];
  const float* f3b = (const float*)d_in[10];
  const float* hth = (const float*)d_in[11];
  const float* qth = (const float*)d_in[12];
  const float* lw  = (const float*)d_in[13];
  const float* lb  = (const float*)d_in[14];
  float* out = (float*)d_out;
  char* ws = (char*)d_ws;

  // ws layout (bytes):
  //   [0, 46476288)                 pool1 (128*6*123*123 f32); reused as fc1 partials (15.7MB)
  //   [46476288, 75053568)          h (128*55815 f32)
  //   [75053568, 78623232)          tmp resize rows (128*28*249 f32)
  //   [78623232, 78684672)          fc1 out (128*120 f32)
  //   [78684672, 78685184)          probs_conv (128 f32)
  float* pool1   = (float*)(ws);
  float* partial = pool1;  // pool1 dead after k_conv2
  float* h       = (float*)(ws + 46476288);
  float* tmp     = (float*)(ws + 75053568);
  float* fc1o    = (float*)(ws + 78623232);
  float* pconv   = (float*)(ws + 78684672);

  k_conv1<<<dim3(8, 8, 128 * 6), 256, 0, stream>>>(x, c1w, c1b, pool1);
  k_conv2<<<dim3(4, 4, 128 * 15), 256, 0, stream>>>(pool1, c2w, c2b, h);
  k_fc1<<<dim3(256), 256, 0, stream>>>(h, f1w, partial);
  k_fc1_reduce<<<dim3(60), 256, 0, stream>>>(partial, f1b, fc1o);
  k_head<<<dim3(128), 128, 0, stream>>>(fc1o, f2w, f2b, f3w, f3b, hth, pconv);
  k_resize_rows<<<dim3(128 * 28), 256, 0, stream>>>(x, tmp);
  k_quanv<<<dim3(128), 256, 0, stream>>>(tmp, qth, lw, lb, pconv, out);
}

// Round 2
// 566.099 us; speedup vs baseline: 1.2847x; 1.2847x over previous
//
#include <hip/hip_runtime.h>
#include <math.h>

#define DEV static __device__ __forceinline__

// ---------------- 4-qubit real-amplitude circuit helpers ----------------
// state index: idx = q0*8 + q1*4 + q2*2 + q3  (wire w <-> bit (8>>w))
// Wire indices are TEMPLATE params so all register-array indices are
// compile-time (runtime-indexed register arrays spill to scratch).
template <int W>
DEV void q_ry(float s[16], float th) {
  float c = cosf(th * 0.5f), sn = sinf(th * 0.5f);
  constexpr int m = 8 >> W;
#pragma unroll
  for (int i = 0; i < 16; ++i) {
    if (!(i & m)) {
      float a = s[i], b = s[i | m];
      s[i] = c * a - sn * b;
      s[i | m] = sn * a + c * b;
    }
  }
}
template <int C, int T>
DEV void q_cnot(float s[16]) {
  constexpr int mc = 8 >> C, mt = 8 >> T;
#pragma unroll
  for (int i = 0; i < 16; ++i) {
    if ((i & mc) && !(i & mt)) {
      float t = s[i]; s[i] = s[i | mt]; s[i | mt] = t;
    }
  }
}
template <int W>
DEV float q_mz(const float s[16]) {
  constexpr int m = 8 >> W;
  float p = 0.f;
#pragma unroll
  for (int i = 0; i < 16; ++i) p += (i & m) ? -s[i] * s[i] : s[i] * s[i];
  return p;
}
DEV void q_layer(float s[16], const float* __restrict__ th) {
  q_ry<0>(s, th[0]); q_cnot<0, 1>(s);
  q_ry<1>(s, th[1]); q_cnot<1, 2>(s);
  q_ry<2>(s, th[2]); q_cnot<2, 3>(s);
  q_ry<3>(s, th[3]); q_cnot<3, 0>(s);
}

// ---------------- conv1 (5x5 s2 p1, 3->6) + relu + pool(2x2 s1) ----------------
// ALL 6 output channels per block; weights via uniform (scalar) global loads.
// x: (128,3,249,249) -> pooled out: (128,6,123,123)
__global__ __launch_bounds__(256) void k_conv1(const float* __restrict__ x,
                                               const float* __restrict__ w,
                                               const float* __restrict__ bia,
                                               float* __restrict__ out) {
  __shared__ float xs[3][37][37];   // input tile (span = 16*2+5)
  __shared__ float ct[6][17][18];   // conv subtile, all channels (+1 pad)
  int b = blockIdx.z;
  int py0 = blockIdx.y * 16, px0 = blockIdx.x * 16;
  int iy0 = py0 * 2 - 1, ix0 = px0 * 2 - 1;
  int tid = threadIdx.x;
  const float* xb = x + (size_t)b * 186003;  // 3*249*249
  for (int idx = tid; idx < 3 * 37 * 37; idx += 256) {
    int ci = idx / 1369, r = (idx % 1369) / 37, cc = idx % 37;
    int iy = iy0 + r, ix = ix0 + cc;
    float v = 0.f;
    if (iy >= 0 && iy < 249 && ix >= 0 && ix < 249)
      v = xb[ci * 62001 + iy * 249 + ix];
    xs[ci][r][cc] = v;
  }
  __syncthreads();
  for (int idx = tid; idx < 17 * 17; idx += 256) {
    int ty = idx / 17, tx = idx % 17;
    float acc[6];
#pragma unroll
    for (int co = 0; co < 6; ++co) acc[co] = bia[co];
#pragma unroll
    for (int ci = 0; ci < 3; ++ci)
#pragma unroll
      for (int ky = 0; ky < 5; ++ky)
#pragma unroll
        for (int kx = 0; kx < 5; ++kx) {
          float v = xs[ci][ty * 2 + ky][tx * 2 + kx];  // 1 LDS read / 6 FMAs
#pragma unroll
          for (int co = 0; co < 6; ++co)
            acc[co] += v * w[co * 75 + ci * 25 + ky * 5 + kx];  // s_load (uniform)
        }
#pragma unroll
    for (int co = 0; co < 6; ++co) ct[co][ty][tx] = acc[co];
  }
  __syncthreads();
  int ty = tid / 16, tx = tid % 16;
  int py = py0 + ty, px = px0 + tx;
  if (py < 123 && px < 123) {
#pragma unroll
    for (int co = 0; co < 6; ++co) {
      float m = fmaxf(fmaxf(ct[co][ty][tx], ct[co][ty][tx + 1]),
                      fmaxf(ct[co][ty + 1][tx], ct[co][ty + 1][tx + 1]));
      out[((size_t)(b * 6 + co) * 123 + py) * 123 + px] = fmaxf(m, 0.f);
    }
  }
}

// ---------------- conv2 (3x3 s2 p1, 6->15) + relu + pool ----------------
// ALL 15 output channels per block; weights via scalar loads.
// in: (128,6,123,123) -> h: (128, 15*61*61=55815) flattened
__global__ __launch_bounds__(256) void k_conv2(const float* __restrict__ in,
                                               const float* __restrict__ w,
                                               const float* __restrict__ bia,
                                               float* __restrict__ out) {
  __shared__ float xs[6][35][35];   // span = 16*2+3
  __shared__ float ct[15][17][18];
  int b = blockIdx.z;
  int py0 = blockIdx.y * 16, px0 = blockIdx.x * 16;
  int iy0 = py0 * 2 - 1, ix0 = px0 * 2 - 1;
  int tid = threadIdx.x;
  const float* ib = in + (size_t)b * 90774;  // 6*123*123
  for (int idx = tid; idx < 6 * 35 * 35; idx += 256) {
    int ci = idx / 1225, r = (idx % 1225) / 35, cc = idx % 35;
    int iy = iy0 + r, ix = ix0 + cc;
    float v = 0.f;
    if (iy >= 0 && iy < 123 && ix >= 0 && ix < 123)
      v = ib[ci * 15129 + iy * 123 + ix];
    xs[ci][r][cc] = v;
  }
  __syncthreads();
  for (int idx = tid; idx < 17 * 17; idx += 256) {
    int ty = idx / 17, tx = idx % 17;
    float acc[15];
#pragma unroll
    for (int co = 0; co < 15; ++co) acc[co] = bia[co];
#pragma unroll
    for (int ci = 0; ci < 6; ++ci)
#pragma unroll
      for (int ky = 0; ky < 3; ++ky)
#pragma unroll
        for (int kx = 0; kx < 3; ++kx) {
          float v = xs[ci][ty * 2 + ky][tx * 2 + kx];  // 1 LDS read / 15 FMAs
#pragma unroll
          for (int co = 0; co < 15; ++co)
            acc[co] += v * w[co * 54 + ci * 9 + ky * 3 + kx];  // s_load
        }
#pragma unroll
    for (int co = 0; co < 15; ++co) ct[co][ty][tx] = acc[co];
  }
  __syncthreads();
  int ty = tid / 16, tx = tid % 16;
  int py = py0 + ty, px = px0 + tx;
  if (py < 61 && px < 61) {
#pragma unroll
    for (int co = 0; co < 15; ++co) {
      float m = fmaxf(fmaxf(ct[co][ty][tx], ct[co][ty][tx + 1]),
                      fmaxf(ct[co][ty + 1][tx], ct[co][ty + 1][tx + 1]));
      out[(size_t)b * 55815 + co * 3721 + py * 61 + px] = fmaxf(m, 0.f);
    }
  }
}

// ---------------- fc1: (128,55815) x (120,55815)^T, split-K partials ----------------
#define KFC 55815
#define NCHUNK 1745  // ceil(55815/32)
__global__ __launch_bounds__(256) void k_fc1(const float* __restrict__ h,
                                             const float* __restrict__ w,
                                             float* __restrict__ partial) {
  __shared__ float hs[128][33];   // +1 pad
  __shared__ float wsd[120][33];
  int tid = threadIdx.x;
  int tb = tid & 31;   // batch lane: batches tb, tb+32, tb+64, tb+96
  int bo = tid >> 5;   // output group: outputs bo*15 .. bo*15+14
  float acc[4][15];
#pragma unroll
  for (int j = 0; j < 4; ++j)
#pragma unroll
    for (int oo = 0; oo < 15; ++oo) acc[j][oo] = 0.f;

  for (int ch = blockIdx.x; ch < NCHUNK; ch += gridDim.x) {
    int k0 = ch * 32;
    for (int idx = tid; idx < 128 * 32; idx += 256) {
      int bb = idx >> 5, kk = idx & 31;
      int k = k0 + kk;
      hs[bb][kk] = (k < KFC) ? h[(size_t)bb * KFC + k] : 0.f;
    }
    for (int idx = tid; idx < 120 * 32; idx += 256) {
      int oo = idx >> 5, kk = idx & 31;
      int k = k0 + kk;
      wsd[oo][kk] = (k < KFC) ? w[(size_t)oo * KFC + k] : 0.f;
    }
    __syncthreads();
#pragma unroll 4
    for (int kk = 0; kk < 32; ++kk) {
      float hv[4], wv[15];
#pragma unroll
      for (int j = 0; j < 4; ++j) hv[j] = hs[tb + 32 * j][kk];
#pragma unroll
      for (int oo = 0; oo < 15; ++oo) wv[oo] = wsd[bo * 15 + oo][kk];
#pragma unroll
      for (int j = 0; j < 4; ++j)
#pragma unroll
        for (int oo = 0; oo < 15; ++oo) acc[j][oo] += hv[j] * wv[oo];
    }
    __syncthreads();
  }
  float* pg = partial + (size_t)blockIdx.x * 15360;
#pragma unroll
  for (int j = 0; j < 4; ++j) {
    int b = tb + 32 * j;
#pragma unroll
    for (int oo = 0; oo < 15; ++oo) pg[b * 120 + bo * 15 + oo] = acc[j][oo];
  }
}

__global__ __launch_bounds__(256) void k_fc1_reduce(const float* __restrict__ partial,
                                                    const float* __restrict__ bias,
                                                    float* __restrict__ outv) {
  int i = blockIdx.x * 256 + threadIdx.x;
  if (i >= 15360) return;
  float a = bias[i % 120];
  for (int g = 0; g < 256; ++g) a += partial[(size_t)g * 15360 + i];
  outv[i] = fmaxf(a, 0.f);  // relu fused
}

// ---------------- fc2 + fc3 + quantum head -> probs_conv ----------------
__global__ __launch_bounds__(128) void k_head(const float* __restrict__ fc1o,
                                              const float* __restrict__ w2,
                                              const float* __restrict__ b2,
                                              const float* __restrict__ w3,
                                              const float* __restrict__ b3,
                                              const float* __restrict__ hth,
                                              float* __restrict__ probs_conv) {
  __shared__ float h1[120];
  __shared__ float h2[84];
  int b = blockIdx.x, tid = threadIdx.x;
  if (tid < 120) h1[tid] = fc1o[b * 120 + tid];  // already relu'd
  __syncthreads();
  if (tid < 84) {
    float a = b2[tid];
    for (int k = 0; k < 120; ++k) a += h1[k] * w2[tid * 120 + k];
    h2[tid] = fmaxf(a, 0.f);
  }
  __syncthreads();
  if (tid == 0) {
    float lg = b3[0];
    for (int j = 0; j < 84; ++j) lg += h2[j] * w3[j];
    float s[16];
#pragma unroll
    for (int i = 0; i < 16; ++i) s[i] = 0.f;
    s[0] = 1.f;
    q_ry<0>(s, lg);
    q_layer(s, hth);
    float z = q_mz<0>(s);
    probs_conv[b] = 1.f / (1.f + expf(-z));
  }
}

// ---------------- resize 249->28 (jax linear+antialias), row pass ----------------
DEV void resize_win(int o, int& i0, int& i1, float& sf, float& inorm) {
  const float invs = 249.0f / 28.0f;   // = kernel_scale (antialias, scale<1)
  sf = ((float)o + 0.5f) * invs - 0.5f;
  i0 = (int)ceilf(sf - invs); if (i0 < 0) i0 = 0;
  i1 = (int)floorf(sf + invs); if (i1 > 248) i1 = 248;
  float nrm = 0.f;
  for (int i = i0; i <= i1; ++i)
    nrm += fmaxf(0.f, 1.f - fabsf(sf - (float)i) * (28.0f / 249.0f));
  inorm = 1.f / nrm;
}

// tmp[b][oy][ix] = sum_iy W[oy][iy] * gray[b][iy][ix]
__global__ __launch_bounds__(256) void k_resize_rows(const float* __restrict__ x,
                                                     float* __restrict__ tmp) {
  int b = blockIdx.x / 28, oy = blockIdx.x % 28;
  int ix = threadIdx.x;
  if (ix >= 249) return;
  int i0, i1; float sf, inorm;
  resize_win(oy, i0, i1, sf, inorm);
  const float* xb = x + (size_t)b * 186003;
  float acc = 0.f;
  for (int iy = i0; iy <= i1; ++iy) {
    float wv = fmaxf(0.f, 1.f - fabsf(sf - (float)iy) * (28.0f / 249.0f)) * inorm;
    float gr = (xb[iy * 249 + ix] + xb[62001 + iy * 249 + ix] +
                xb[124002 + iy * 249 + ix]) * (1.0f / 3.0f);
    acc += wv * gr;
  }
  tmp[((size_t)b * 28 + oy) * 249 + ix] = acc;
}

// ---------------- col pass + patches + per-patch circuits + lin + combine ----------------
__global__ __launch_bounds__(256) void k_quanv(const float* __restrict__ tmp,
                                               const float* __restrict__ qth,
                                               const float* __restrict__ lw,
                                               const float* __restrict__ lb,
                                               const float* __restrict__ probs_conv,
                                               float* __restrict__ out) {
  __shared__ float g[784];
  __shared__ float red[4];
  int b = blockIdx.x, tid = threadIdx.x;
  for (int idx = tid; idx < 784; idx += 256) {
    int oy = idx / 28, ox = idx % 28;
    int i0, i1; float sf, inorm;
    resize_win(ox, i0, i1, sf, inorm);
    const float* tr = tmp + ((size_t)b * 28 + oy) * 249;
    float acc = 0.f;
    for (int i = i0; i <= i1; ++i)
      acc += fmaxf(0.f, 1.f - fabsf(sf - (float)i) * (28.0f / 249.0f)) * inorm * tr[i];
    g[idx] = acc;
  }
  __syncthreads();
  float part = 0.f;
  if (tid < 196) {
    int pi = tid / 14, pj = tid % 14;
    float v0 = g[(2 * pi) * 28 + 2 * pj];
    float v1 = g[(2 * pi) * 28 + 2 * pj + 1];
    float v2 = g[(2 * pi + 1) * 28 + 2 * pj];
    float v3 = g[(2 * pi + 1) * 28 + 2 * pj + 1];
    float s[16];
#pragma unroll
    for (int i = 0; i < 16; ++i) s[i] = 0.f;
    s[0] = 1.f;
    q_ry<0>(s, v0); q_ry<1>(s, v1); q_ry<2>(s, v2); q_ry<3>(s, v3);
    q_layer(s, qth);
    float z0 = q_mz<0>(s), z1 = q_mz<1>(s), z2 = q_mz<2>(s), z3 = q_mz<3>(s);
    const float* lwp = lw + tid * 4;
    part = z0 * lwp[0] + z1 * lwp[1] + z2 * lwp[2] + z3 * lwp[3];
  }
#pragma unroll
  for (int off = 32; off > 0; off >>= 1) part += __shfl_down(part, off, 64);
  if ((tid & 63) == 0) red[tid >> 6] = part;
  __syncthreads();
  if (tid == 0) {
    float tot = red[0] + red[1] + red[2] + red[3] + lb[0];
    float pq = 1.f / (1.f + expf(-tot));
    float pr = 0.5f * (probs_conv[b] + pq);
    out[b * 2 + 0] = pr;
    out[b * 2 + 1] = 1.f - pr;
  }
}

// ---------------- launch ----------------
extern "C" void kernel_launch(void* const* d_in, const int* in_sizes, int n_in,
                              void* d_out, int out_size, void* d_ws, size_t ws_size,
                              hipStream_t stream) {
  const float* x   = (const float*)d_in[0];
  const float* c1w = (const float*)d_in[1];
  const float* c1b = (const float*)d_in[2];
  const float* c2w = (const float*)d_in[3];
  const float* c2b = (const float*)d_in[4];
  const float* f1w = (const float*)d_in[5];
  const float* f1b = (const float*)d_in[6];
  const float* f2w = (const float*)d_in[7];
  const float* f2b = (const float*)d_in[8];
  const float* f3w = (const float*)d_in[9];
  const float* f3b = (const float*)d_in[10];
  const float* hth = (const float*)d_in[11];
  const float* qth = (const float*)d_in[12];
  const float* lw  = (const float*)d_in[13];
  const float* lb  = (const float*)d_in[14];
  float* out = (float*)d_out;
  char* ws = (char*)d_ws;

  // ws layout (bytes):
  //   [0, 46476288)        pool1 (128*6*123*123 f32); reused as fc1 partials (15.7MB)
  //   [46476288, 75053568) h (128*55815 f32)
  //   [75053568, 78623232) tmp resize rows (128*28*249 f32)
  //   [78623232, 78684672) fc1 out (128*120 f32)
  //   [78684672, 78685184) probs_conv (128 f32)
  float* pool1   = (float*)(ws);
  float* partial = pool1;  // pool1 dead after k_conv2
  float* h       = (float*)(ws + 46476288);
  float* tmp     = (float*)(ws + 75053568);
  float* fc1o    = (float*)(ws + 78623232);
  float* pconv   = (float*)(ws + 78684672);

  k_conv1<<<dim3(8, 8, 128), 256, 0, stream>>>(x, c1w, c1b, pool1);
  k_conv2<<<dim3(4, 4, 128), 256, 0, stream>>>(pool1, c2w, c2b, h);
  k_fc1<<<dim3(256), 256, 0, stream>>>(h, f1w, partial);
  k_fc1_reduce<<<dim3(60), 256, 0, stream>>>(partial, f1b, fc1o);
  k_head<<<dim3(128), 128, 0, stream>>>(fc1o, f2w, f2b, f3w, f3b, hth, pconv);
  k_resize_rows<<<dim3(128 * 28), 256, 0, stream>>>(x, tmp);
  k_quanv<<<dim3(128), 256, 0, stream>>>(tmp, qth, lw, lb, pconv, out);
}

// Round 3
// 477.743 us; speedup vs baseline: 1.5222x; 1.1849x over previous
//
#include <hip/hip_runtime.h>
#include <math.h>

#define DEV static __device__ __forceinline__

// ---------------- 4-qubit real-amplitude circuit helpers ----------------
template <int W>
DEV void q_ry(float s[16], float th) {
  float c = cosf(th * 0.5f), sn = sinf(th * 0.5f);
  constexpr int m = 8 >> W;
#pragma unroll
  for (int i = 0; i < 16; ++i) {
    if (!(i & m)) {
      float a = s[i], b = s[i | m];
      s[i] = c * a - sn * b;
      s[i | m] = sn * a + c * b;
    }
  }
}
template <int C, int T>
DEV void q_cnot(float s[16]) {
  constexpr int mc = 8 >> C, mt = 8 >> T;
#pragma unroll
  for (int i = 0; i < 16; ++i) {
    if ((i & mc) && !(i & mt)) {
      float t = s[i]; s[i] = s[i | mt]; s[i | mt] = t;
    }
  }
}
template <int W>
DEV float q_mz(const float s[16]) {
  constexpr int m = 8 >> W;
  float p = 0.f;
#pragma unroll
  for (int i = 0; i < 16; ++i) p += (i & m) ? -s[i] * s[i] : s[i] * s[i];
  return p;
}
DEV void q_layer(float s[16], const float* __restrict__ th) {
  q_ry<0>(s, th[0]); q_cnot<0, 1>(s);
  q_ry<1>(s, th[1]); q_cnot<1, 2>(s);
  q_ry<2>(s, th[2]); q_cnot<2, 3>(s);
  q_ry<3>(s, th[3]); q_cnot<3, 0>(s);
}

// ---------------- conv1 (5x5 s2 p1, 3->6) + relu + pool(2x2 s1) ----------------
// Strip-mined: thread = (co, conv-row), 17 outputs/thread, weights in regs per sweep.
// x: (128,3,249,249) -> pooled out: (128,6,123,123)
__global__ __launch_bounds__(256) void k_conv1(const float* __restrict__ x,
                                               const float* __restrict__ w,
                                               const float* __restrict__ bia,
                                               float* __restrict__ out) {
  __shared__ float xs[3][37][37];   // input tile (span = 16*2+5)
  __shared__ float wt[75 * 6];      // transposed weights [j][co]
  __shared__ float ct[6][17][18];   // conv subtile (+1 pad)
  int b = blockIdx.z;
  int py0 = blockIdx.y * 16, px0 = blockIdx.x * 16;
  int iy0 = py0 * 2 - 1, ix0 = px0 * 2 - 1;
  int tid = threadIdx.x;
  for (int i = tid; i < 450; i += 256) {
    int j = i / 6, co = i % 6;
    wt[i] = w[co * 75 + j];
  }
  const float* xb = x + (size_t)b * 186003;  // 3*249*249
  for (int idx = tid; idx < 3 * 37 * 37; idx += 256) {
    int ci = idx / 1369, r = (idx % 1369) / 37, cc = idx % 37;
    int iy = iy0 + r, ix = ix0 + cc;
    float v = 0.f;
    if (iy >= 0 && iy < 249 && ix >= 0 && ix < 249)
      v = xb[ci * 62001 + iy * 249 + ix];
    xs[ci][r][cc] = v;
  }
  __syncthreads();
  if (tid < 102) {                 // 6 co * 17 rows
    int co = tid % 6, ty = tid / 6;
    float acc[17];
    float bv = bia[co];
#pragma unroll
    for (int t = 0; t < 17; ++t) acc[t] = bv;
#pragma unroll
    for (int ci = 0; ci < 3; ++ci)
#pragma unroll
      for (int ky = 0; ky < 5; ++ky) {
        int y = ty * 2 + ky;
        const int jb = (ci * 25 + ky * 5) * 6 + co;
        float w0 = wt[jb], w1 = wt[jb + 6], w2 = wt[jb + 12],
              w3 = wt[jb + 18], w4 = wt[jb + 24];
        float xp0 = xs[ci][y][0], xp1 = xs[ci][y][1];
#pragma unroll
        for (int tx = 0; tx < 17; ++tx) {
          float xa = xs[ci][y][2 * tx + 2];
          float xb2 = xs[ci][y][2 * tx + 3];
          float xc = xs[ci][y][2 * tx + 4];
          acc[tx] += xp0 * w0 + xp1 * w1 + xa * w2 + xb2 * w3 + xc * w4;
          xp0 = xa; xp1 = xb2;
        }
      }
#pragma unroll
    for (int tx = 0; tx < 17; ++tx) ct[co][ty][tx] = acc[tx];
  }
  __syncthreads();
  if (tid < 96) {                  // 6 co * 16 pooled rows
    int co = tid % 6, ty = tid / 6;
    int py = py0 + ty;
    if (py < 123) {
      float* op = out + ((size_t)(b * 6 + co) * 123 + py) * 123 + px0;
#pragma unroll
      for (int tx = 0; tx < 16; ++tx) {
        if (px0 + tx < 123) {
          float m = fmaxf(fmaxf(ct[co][ty][tx], ct[co][ty][tx + 1]),
                          fmaxf(ct[co][ty + 1][tx], ct[co][ty + 1][tx + 1]));
          op[tx] = fmaxf(m, 0.f);
        }
      }
    }
  }
}

// ---------------- conv2 (3x3 s2 p1, 6->15) + relu + pool ----------------
// in: (128,6,123,123) -> h: (128, 15*61*61=55815) flattened
__global__ __launch_bounds__(256) void k_conv2(const float* __restrict__ in,
                                               const float* __restrict__ w,
                                               const float* __restrict__ bia,
                                               float* __restrict__ out) {
  __shared__ float xs[6][35][35];   // span = 16*2+3
  __shared__ float wt[54 * 15];     // transposed weights [j][co]
  __shared__ float ct[15][17][18];
  int b = blockIdx.z;
  int py0 = blockIdx.y * 16, px0 = blockIdx.x * 16;
  int iy0 = py0 * 2 - 1, ix0 = px0 * 2 - 1;
  int tid = threadIdx.x;
  for (int i = tid; i < 810; i += 256) {
    int j = i / 15, co = i % 15;
    wt[i] = w[co * 54 + j];
  }
  const float* ib = in + (size_t)b * 90774;  // 6*123*123
  for (int idx = tid; idx < 6 * 35 * 35; idx += 256) {
    int ci = idx / 1225, r = (idx % 1225) / 35, cc = idx % 35;
    int iy = iy0 + r, ix = ix0 + cc;
    float v = 0.f;
    if (iy >= 0 && iy < 123 && ix >= 0 && ix < 123)
      v = ib[ci * 15129 + iy * 123 + ix];
    xs[ci][r][cc] = v;
  }
  __syncthreads();
  if (tid < 255) {                 // 15 co * 17 rows
    int co = tid % 15, ty = tid / 15;
    float acc[17];
    float bv = bia[co];
#pragma unroll
    for (int t = 0; t < 17; ++t) acc[t] = bv;
#pragma unroll
    for (int ci = 0; ci < 6; ++ci)
#pragma unroll
      for (int ky = 0; ky < 3; ++ky) {
        int y = ty * 2 + ky;
        const int jb = (ci * 9 + ky * 3) * 15 + co;
        float w0 = wt[jb], w1 = wt[jb + 15], w2 = wt[jb + 30];
        float xp = xs[ci][y][0];
#pragma unroll
        for (int tx = 0; tx < 17; ++tx) {
          float xa = xs[ci][y][2 * tx + 1];
          float xb2 = xs[ci][y][2 * tx + 2];
          acc[tx] += xp * w0 + xa * w1 + xb2 * w2;
          xp = xb2;
        }
      }
#pragma unroll
    for (int tx = 0; tx < 17; ++tx) ct[co][ty][tx] = acc[tx];
  }
  __syncthreads();
  if (tid < 240) {                 // 15 co * 16 pooled rows
    int co = tid % 15, ty = tid / 15;
    int py = py0 + ty;
    if (py < 61) {
      float* op = out + (size_t)b * 55815 + co * 3721 + py * 61 + px0;
#pragma unroll
      for (int tx = 0; tx < 16; ++tx) {
        if (px0 + tx < 61) {
          float m = fmaxf(fmaxf(ct[co][ty][tx], ct[co][ty][tx + 1]),
                          fmaxf(ct[co][ty + 1][tx], ct[co][ty + 1][tx + 1]));
          op[tx] = fmaxf(m, 0.f);
        }
      }
    }
  }
}

// ---------------- fc1: (128,55815) x (120,55815)^T, split-K partials ----------------
#define KFC 55815
#define NCHUNK 1745  // ceil(55815/32)
__global__ __launch_bounds__(256) void k_fc1(const float* __restrict__ h,
                                             const float* __restrict__ w,
                                             float* __restrict__ partial) {
  __shared__ float hs[128][33];   // +1 pad
  __shared__ float wsd[120][33];
  int tid = threadIdx.x;
  int tb = tid & 31;   // batch lane
  int bo = tid >> 5;   // output group: outputs bo*15 .. bo*15+14
  float acc[4][15];
#pragma unroll
  for (int j = 0; j < 4; ++j)
#pragma unroll
    for (int oo = 0; oo < 15; ++oo) acc[j][oo] = 0.f;

  for (int ch = blockIdx.x; ch < NCHUNK; ch += gridDim.x) {
    int k0 = ch * 32;
    for (int idx = tid; idx < 128 * 32; idx += 256) {
      int bb = idx >> 5, kk = idx & 31;
      int k = k0 + kk;
      hs[bb][kk] = (k < KFC) ? h[(size_t)bb * KFC + k] : 0.f;
    }
    for (int idx = tid; idx < 120 * 32; idx += 256) {
      int oo = idx >> 5, kk = idx & 31;
      int k = k0 + kk;
      wsd[oo][kk] = (k < KFC) ? w[(size_t)oo * KFC + k] : 0.f;
    }
    __syncthreads();
#pragma unroll 4
    for (int kk = 0; kk < 32; ++kk) {
      float hv[4], wv[15];
#pragma unroll
      for (int j = 0; j < 4; ++j) hv[j] = hs[tb + 32 * j][kk];
#pragma unroll
      for (int oo = 0; oo < 15; ++oo) wv[oo] = wsd[bo * 15 + oo][kk];
#pragma unroll
      for (int j = 0; j < 4; ++j)
#pragma unroll
        for (int oo = 0; oo < 15; ++oo) acc[j][oo] += hv[j] * wv[oo];
    }
    __syncthreads();
  }
  float* pg = partial + (size_t)blockIdx.x * 15360;
#pragma unroll
  for (int j = 0; j < 4; ++j) {
    int b = tb + 32 * j;
#pragma unroll
    for (int oo = 0; oo < 15; ++oo) pg[b * 120 + bo * 15 + oo] = acc[j][oo];
  }
}

__global__ __launch_bounds__(256) void k_fc1_reduce(const float* __restrict__ partial,
                                                    const float* __restrict__ bias,
                                                    float* __restrict__ outv) {
  int i = blockIdx.x * 256 + threadIdx.x;
  if (i >= 15360) return;
  float a = bias[i % 120];
  for (int g = 0; g < 256; ++g) a += partial[(size_t)g * 15360 + i];
  outv[i] = fmaxf(a, 0.f);  // relu fused
}

// ---------------- fc2 + fc3 + quantum head -> probs_conv ----------------
__global__ __launch_bounds__(128) void k_head(const float* __restrict__ fc1o,
                                              const float* __restrict__ w2,
                                              const float* __restrict__ b2,
                                              const float* __restrict__ w3,
                                              const float* __restrict__ b3,
                                              const float* __restrict__ hth,
                                              float* __restrict__ probs_conv) {
  __shared__ float h1[120];
  __shared__ float h2[84];
  int b = blockIdx.x, tid = threadIdx.x;
  if (tid < 120) h1[tid] = fc1o[b * 120 + tid];  // already relu'd
  __syncthreads();
  if (tid < 84) {
    float a = b2[tid];
    for (int k = 0; k < 120; ++k) a += h1[k] * w2[tid * 120 + k];
    h2[tid] = fmaxf(a, 0.f);
  }
  __syncthreads();
  if (tid == 0) {
    float lg = b3[0];
    for (int j = 0; j < 84; ++j) lg += h2[j] * w3[j];
    float s[16];
#pragma unroll
    for (int i = 0; i < 16; ++i) s[i] = 0.f;
    s[0] = 1.f;
    q_ry<0>(s, lg);
    q_layer(s, hth);
    float z = q_mz<0>(s);
    probs_conv[b] = 1.f / (1.f + expf(-z));
  }
}

// ---------------- resize 249->28 (jax linear+antialias), row pass ----------------
DEV void resize_win(int o, int& i0, int& i1, float& sf, float& inorm) {
  const float invs = 249.0f / 28.0f;
  sf = ((float)o + 0.5f) * invs - 0.5f;
  i0 = (int)ceilf(sf - invs); if (i0 < 0) i0 = 0;
  i1 = (int)floorf(sf + invs); if (i1 > 248) i1 = 248;
  float nrm = 0.f;
  for (int i = i0; i <= i1; ++i)
    nrm += fmaxf(0.f, 1.f - fabsf(sf - (float)i) * (28.0f / 249.0f));
  inorm = 1.f / nrm;
}

// tmp[b][oy][ix] = sum_iy W[oy][iy] * gray[b][iy][ix]
__global__ __launch_bounds__(256) void k_resize_rows(const float* __restrict__ x,
                                                     float* __restrict__ tmp) {
  int b = blockIdx.x / 28, oy = blockIdx.x % 28;
  int ix = threadIdx.x;
  if (ix >= 249) return;
  int i0, i1; float sf, inorm;
  resize_win(oy, i0, i1, sf, inorm);
  const float* xb = x + (size_t)b * 186003;
  float acc = 0.f;
  for (int iy = i0; iy <= i1; ++iy) {
    float wv = fmaxf(0.f, 1.f - fabsf(sf - (float)iy) * (28.0f / 249.0f)) * inorm;
    float gr = (xb[iy * 249 + ix] + xb[62001 + iy * 249 + ix] +
                xb[124002 + iy * 249 + ix]) * (1.0f / 3.0f);
    acc += wv * gr;
  }
  tmp[((size_t)b * 28 + oy) * 249 + ix] = acc;
}

// ---------------- col pass + patches + per-patch circuits + lin + combine ----------------
__global__ __launch_bounds__(256) void k_quanv(const float* __restrict__ tmp,
                                               const float* __restrict__ qth,
                                               const float* __restrict__ lw,
                                               const float* __restrict__ lb,
                                               const float* __restrict__ probs_conv,
                                               float* __restrict__ out) {
  __shared__ float g[784];
  __shared__ float red[4];
  int b = blockIdx.x, tid = threadIdx.x;
  for (int idx = tid; idx < 784; idx += 256) {
    int oy = idx / 28, ox = idx % 28;
    int i0, i1; float sf, inorm;
    resize_win(ox, i0, i1, sf, inorm);
    const float* tr = tmp + ((size_t)b * 28 + oy) * 249;
    float acc = 0.f;
    for (int i = i0; i <= i1; ++i)
      acc += fmaxf(0.f, 1.f - fabsf(sf - (float)i) * (28.0f / 249.0f)) * inorm * tr[i];
    g[idx] = acc;
  }
  __syncthreads();
  float part = 0.f;
  if (tid < 196) {
    int pi = tid / 14, pj = tid % 14;
    float v0 = g[(2 * pi) * 28 + 2 * pj];
    float v1 = g[(2 * pi) * 28 + 2 * pj + 1];
    float v2 = g[(2 * pi + 1) * 28 + 2 * pj];
    float v3 = g[(2 * pi + 1) * 28 + 2 * pj + 1];
    float s[16];
#pragma unroll
    for (int i = 0; i < 16; ++i) s[i] = 0.f;
    s[0] = 1.f;
    q_ry<0>(s, v0); q_ry<1>(s, v1); q_ry<2>(s, v2); q_ry<3>(s, v3);
    q_layer(s, qth);
    float z0 = q_mz<0>(s), z1 = q_mz<1>(s), z2 = q_mz<2>(s), z3 = q_mz<3>(s);
    const float* lwp = lw + tid * 4;
    part = z0 * lwp[0] + z1 * lwp[1] + z2 * lwp[2] + z3 * lwp[3];
  }
#pragma unroll
  for (int off = 32; off > 0; off >>= 1) part += __shfl_down(part, off, 64);
  if ((tid & 63) == 0) red[tid >> 6] = part;
  __syncthreads();
  if (tid == 0) {
    float tot = red[0] + red[1] + red[2] + red[3] + lb[0];
    float pq = 1.f / (1.f + expf(-tot));
    float pr = 0.5f * (probs_conv[b] + pq);
    out[b * 2 + 0] = pr;
    out[b * 2 + 1] = 1.f - pr;
  }
}

// ---------------- launch ----------------
extern "C" void kernel_launch(void* const* d_in, const int* in_sizes, int n_in,
                              void* d_out, int out_size, void* d_ws, size_t ws_size,
                              hipStream_t stream) {
  const float* x   = (const float*)d_in[0];
  const float* c1w = (const float*)d_in[1];
  const float* c1b = (const float*)d_in[2];
  const float* c2w = (const float*)d_in[3];
  const float* c2b = (const float*)d_in[4];
  const float* f1w = (const float*)d_in[5];
  const float* f1b = (const float*)d_in[6];
  const float* f2w = (const float*)d_in[7];
  const float* f2b = (const float*)d_in[8];
  const float* f3w = (const float*)d_in[9];
  const float* f3b = (const float*)d_in[10];
  const float* hth = (const float*)d_in[11];
  const float* qth = (const float*)d_in[12];
  const float* lw  = (const float*)d_in[13];
  const float* lb  = (const float*)d_in[14];
  float* out = (float*)d_out;
  char* ws = (char*)d_ws;

  float* pool1   = (float*)(ws);
  float* partial = pool1;  // pool1 dead after k_conv2
  float* h       = (float*)(ws + 46476288);
  float* tmp     = (float*)(ws + 75053568);
  float* fc1o    = (float*)(ws + 78623232);
  float* pconv   = (float*)(ws + 78684672);

  k_conv1<<<dim3(8, 8, 128), 256, 0, stream>>>(x, c1w, c1b, pool1);
  k_conv2<<<dim3(4, 4, 128), 256, 0, stream>>>(pool1, c2w, c2b, h);
  k_fc1<<<dim3(256), 256, 0, stream>>>(h, f1w, partial);
  k_fc1_reduce<<<dim3(60), 256, 0, stream>>>(partial, f1b, fc1o);
  k_head<<<dim3(128), 128, 0, stream>>>(fc1o, f2w, f2b, f3w, f3b, hth, pconv);
  k_resize_rows<<<dim3(128 * 28), 256, 0, stream>>>(x, tmp);
  k_quanv<<<dim3(128), 256, 0, stream>>>(tmp, qth, lw, lb, pconv, out);
}